// Round 27
// baseline (1624.783 us; speedup 1.0000x reference)
//
#include <hip/hip_runtime.h>
#include <hip/hip_bf16.h>
#include <math.h>

typedef unsigned short u16;
typedef unsigned int u32;
typedef _Float16 f16x8 __attribute__((ext_vector_type(8)));
typedef float f32x4 __attribute__((ext_vector_type(4)));

#define DEV static __device__ __forceinline__

constexpr int D = 768;
constexpr int HH = 12;
constexpr int KD = 64;
constexpr int T = 64;
constexpr int NSEQ = 512;
constexpr int MROWS = NSEQ * T;   // 32768
constexpr int DFF = 3072;
constexpr int PP = 16;

DEV u16 f2h(float f){ union{_Float16 h; u16 u;} c; c.h = (_Float16)f; return c.u; }
DEV float h2f(u16 u){ union{u16 u; _Float16 h;} c; c.u = u; return (float)c.h; }
DEV void gld_lds16(const u16* g, u16* l){
  __builtin_amdgcn_global_load_lds((const __attribute__((address_space(1))) void*)g,
                                   (__attribute__((address_space(3))) void*)l, 16, 0, 0);
}
// XOR-swizzled LDS element offset for [128][32] fp16 tiles: slot = kgrp ^ q(row),
// q(r) = (r ^ (r>>2)) & 3 -> 16-lane frag reads spread over 8 banks (2-way, free).
DEV int lsw(int row, int kgrp){ return row * 32 + ((((row >> 2) ^ row) & 3) ^ kgrp) * 8; }

// ---------------- batched transpose: 7 fp32 [D][D] -> fp16 [D][D]^T ----------------
struct TpArgs { const float* src[7]; u16* dst[7]; };
__global__ __launch_bounds__(256) void k_transpose7(TpArgs a){
  __shared__ float tile[32][33];
  int z = blockIdx.z;
  const float* W = a.src[z];
  u16* WT = a.dst[z];
  int c0 = blockIdx.x * 32, r0 = blockIdx.y * 32;
  int tx = threadIdx.x, ty = threadIdx.y;
  #pragma unroll
  for (int i = 0; i < 32; i += 8)
    tile[ty + i][tx] = W[(size_t)(r0 + ty + i) * D + (c0 + tx)];
  __syncthreads();
  #pragma unroll
  for (int i = 0; i < 32; i += 8)
    WT[(size_t)(c0 + ty + i) * D + (r0 + tx)] = f2h(tile[tx][ty + i]);
}

// ---------------- transpose fp32 [R][C] -> fp16 [C][R] ----------------
__global__ __launch_bounds__(256) void k_transpose(const float* __restrict__ W, u16* __restrict__ WT,
                                                   int R, int C){
  __shared__ float tile[32][33];
  int c0 = blockIdx.x * 32, r0 = blockIdx.y * 32;
  int tx = threadIdx.x, ty = threadIdx.y;
  #pragma unroll
  for (int i = 0; i < 32; i += 8)
    tile[ty + i][tx] = W[(size_t)(r0 + ty + i) * C + (c0 + tx)];
  __syncthreads();
  #pragma unroll
  for (int i = 0; i < 32; i += 8)
    WT[(size_t)(c0 + ty + i) * R + (r0 + tx)] = f2h(tile[tx][ty + i]);
}

// ---------------- positional embedding [T][D] ----------------
__global__ void k_pe(float* __restrict__ pe){
  int idx = blockIdx.x * 256 + threadIdx.x;
  if (idx >= T * D) return;
  int t = idx / D, d = idx % D;
  float dv = __expf((float)(d & ~1) * (-9.210340371976184f / (float)D));
  float ang = (float)t * dv;
  pe[idx] = (d & 1) ? cosf(ang) : sinf(ang);
}

// ---------------- fp16 mu planes ----------------
struct MuArgs { const float* mu[6]; };
__global__ __launch_bounds__(256) void k_mu16(MuArgs a, u16* __restrict__ mu16){
  int z = blockIdx.x;
  #pragma unroll
  for (int j = 0; j < 3; j++){
    int d = threadIdx.x + j * 256;
    mu16[z * D + d] = f2h(a.mu[z][d]);
  }
}

// ---------------- patch embed + LN1, wave-per-row: h fp32 + xx fp16 ----------------
__global__ __launch_bounds__(256) void k_patch_ln(const float* __restrict__ x, const float* __restrict__ Wp,
                                                  const float* __restrict__ bp, const float* __restrict__ pe,
                                                  const float* __restrict__ g, const float* __restrict__ b,
                                                  float* __restrict__ h, u16* __restrict__ xx16){
  int lane = threadIdx.x & 63;
  int row = blockIdx.x * 4 + (threadIdx.x >> 6);
  int t = row & (T - 1);
  const float* xr = x + (size_t)row * PP;
  float xs[PP];
  #pragma unroll
  for (int p = 0; p < PP; p++) xs[p] = xr[p];
  float v[12], s = 0.f, sq = 0.f;
  #pragma unroll
  for (int j = 0; j < 12; j++){
    int d = lane + j * 64;
    float acc = bp[d] + pe[t * D + d];
    #pragma unroll
    for (int p = 0; p < PP; p++) acc = fmaf(xs[p], Wp[p * D + d], acc);
    v[j] = acc; s += acc; sq = fmaf(acc, acc, sq);
  }
  #pragma unroll
  for (int o = 32; o; o >>= 1){ s += __shfl_xor(s, o); sq += __shfl_xor(sq, o); }
  float mean = s * (1.f / 768.f);
  float rstd = rsqrtf(sq * (1.f / 768.f) - mean * mean + 1e-5f);
  float* hrow = h + (size_t)row * D;
  u16* xrow = xx16 + (size_t)row * D;
  #pragma unroll
  for (int j = 0; j < 12; j++){
    int d = lane + j * 64;
    hrow[d] = v[j];
    xrow[d] = f2h((v[j] - mean) * rstd * g[d] + b[d]);
  }
}

// ---------------- LN2 + token-shift lerp fused -> fp16 xk ----------------
__global__ __launch_bounds__(256) void k_ln2(const float* __restrict__ X, const float* __restrict__ g,
                                             const float* __restrict__ b, const float* __restrict__ mu,
                                             u16* __restrict__ out){
  int lane = threadIdx.x & 63;
  int row = blockIdx.x * 4 + (threadIdx.x >> 6);
  int t = row & (T - 1);
  const float* xr = X + (size_t)row * D;
  float v[12], s = 0.f, sq = 0.f;
  #pragma unroll
  for (int j = 0; j < 12; j++){ v[j] = xr[lane + j * 64]; s += v[j]; sq += v[j] * v[j]; }
  #pragma unroll
  for (int o = 32; o; o >>= 1){ s += __shfl_xor(s, o); sq += __shfl_xor(sq, o); }
  float mean = s * (1.f / 768.f);
  float rstd = rsqrtf(sq * (1.f / 768.f) - mean * mean + 1e-5f);
  float p[12], meanp = 0.f, rstdp = 0.f;
  if (t){
    const float* xp = xr - D;
    float sp = 0.f, sqp = 0.f;
    #pragma unroll
    for (int j = 0; j < 12; j++){ p[j] = xp[lane + j * 64]; sp += p[j]; sqp += p[j] * p[j]; }
    #pragma unroll
    for (int o = 32; o; o >>= 1){ sp += __shfl_xor(sp, o); sqp += __shfl_xor(sqp, o); }
    meanp = sp * (1.f / 768.f);
    rstdp = rsqrtf(sqp * (1.f / 768.f) - meanp * meanp + 1e-5f);
  }
  u16* orow = out + (size_t)row * D;
  #pragma unroll
  for (int j = 0; j < 12; j++){
    int d = lane + j * 64;
    float cm = (v[j] - mean) * rstd * g[d] + b[d];
    float cp = t ? (p[j] - meanp) * rstdp * g[d] + b[d] : 0.f;
    orow[d] = f2h(cm + (cp - cm) * mu[d]);
  }
}

// ---------------- fp16 GEMM, double-buffered LDS, 1 barrier/K-step (T3 2-phase) ----------------
// ACT: 3 relu^2->f16, 4 add->f32
template<int ACT>
__global__ __launch_bounds__(256) void k_g16(const u16* __restrict__ A, const u16* __restrict__ BT,
                                             u16* __restrict__ outH, float* __restrict__ outF,
                                             int Kd, int Nc){
  __shared__ __align__(16) u16 As[2][128 * 32];
  __shared__ __align__(16) u16 Bs[2][128 * 32];
  int tid = threadIdx.x;
  int m0 = blockIdx.x * 128, n0 = blockIdx.y * 128;
  int wv = tid >> 6, lane = tid & 63;
  int wr = (wv >> 1) * 64, wc = (wv & 1) * 64;
  int lr = lane & 15, kgrp = lane >> 4;
  int r0 = wv * 16 + (lane >> 2);
  int cbg = ((((r0 >> 2) ^ r0) & 3) ^ (lane & 3)) * 8;   // pre-swizzled global col
  const u16* sA0 = A + (size_t)(m0 + r0) * Kd + cbg;
  const u16* sA1 = A + (size_t)(m0 + r0 + 64) * Kd + cbg;
  const u16* sB0 = BT + (size_t)(n0 + r0) * Kd + cbg;
  const u16* sB1 = BT + (size_t)(n0 + r0 + 64) * Kd + cbg;
  int cb = (lane & 3) * 8;
  int o0 = r0 * 32 + cb, o1 = (r0 + 64) * 32 + cb;
  f32x4 acc[4][4] = {};
  int NT = Kd >> 5;

  gld_lds16(sA0, &As[0][o0]);
  gld_lds16(sA1, &As[0][o1]);
  gld_lds16(sB0, &Bs[0][o0]);
  gld_lds16(sB1, &Bs[0][o1]);
  __syncthreads();
  int cur = 0;
  for (int kt = 0; kt < NT; kt++){
    if (kt + 1 < NT){
      int k0 = (kt + 1) << 5;
      gld_lds16(sA0 + k0, &As[cur ^ 1][o0]);
      gld_lds16(sA1 + k0, &As[cur ^ 1][o1]);
      gld_lds16(sB0 + k0, &Bs[cur ^ 1][o0]);
      gld_lds16(sB1 + k0, &Bs[cur ^ 1][o1]);
    }
    f16x8 af[4], bf[4];
    #pragma unroll
    for (int mi = 0; mi < 4; mi++) af[mi] = *(const f16x8*)&As[cur][lsw(wr + mi * 16 + lr, kgrp)];
    #pragma unroll
    for (int ni = 0; ni < 4; ni++) bf[ni] = *(const f16x8*)&Bs[cur][lsw(wc + ni * 16 + lr, kgrp)];
    #pragma unroll
    for (int mi = 0; mi < 4; mi++){
      #pragma unroll
      for (int ni = 0; ni < 4; ni++){
        acc[mi][ni] = __builtin_amdgcn_mfma_f32_16x16x32_f16(af[mi], bf[ni], acc[mi][ni], 0, 0, 0);
      }
    }
    __syncthreads();
    cur ^= 1;
  }

  int rowb = m0 + wr + (lane >> 4) * 4;
  int colb = n0 + wc + lr;
  #pragma unroll
  for (int mi = 0; mi < 4; mi++){
    #pragma unroll
    for (int ni = 0; ni < 4; ni++){
      int gcol = colb + ni * 16;
      #pragma unroll
      for (int i = 0; i < 4; i++){
        int grow = rowb + mi * 16 + i;
        float xv = acc[mi][ni][i];
        size_t o = (size_t)grow * Nc + gcol;
        if (ACT == 3){ float rl = fmaxf(xv, 0.f); outH[o] = f2h(rl * rl); }
        else outF[o] += xv;
      }
    }
  }
}

// ---------------- mixing GEMM: fused fp16 lerp A-stage, double-buffered, async-split ----------------
// act: 0 none->f16, 1 (x+bias)->f16 raw (w preact), 2 sigmoid(x+bias)->f16
struct MixArgs {
  const u16* b[6]; const float* bias[6]; const u16* mu16;
  u16* outh[6]; int act[6];
};
__global__ __launch_bounds__(256) void k_mix_lerp(const u16* __restrict__ X16, MixArgs args, int Kd, int Nc){
  __shared__ __align__(16) u16 As[2][128 * 32];
  __shared__ __align__(16) u16 Bs[2][128 * 32];
  int tid = threadIdx.x, z = blockIdx.z;
  const u16* BT = args.b[z];
  const u16* mu16 = args.mu16 + z * D;
  int m0 = blockIdx.x * 128, n0 = blockIdx.y * 128;
  int wv = tid >> 6, lane = tid & 63;
  int wr = (wv >> 1) * 64, wc = (wv & 1) * 64;
  int lr = lane & 15, kgrp = lane >> 4;
  int r0 = wv * 16 + (lane >> 2);
  int cbg = ((((r0 >> 2) ^ r0) & 3) ^ (lane & 3)) * 8;
  const u16* sB0 = BT + (size_t)(n0 + r0) * Kd + cbg;
  const u16* sB1 = BT + (size_t)(n0 + r0 + 64) * Kd + cbg;
  int cb = (lane & 3) * 8;
  int o0 = r0 * 32 + cb, o1 = (r0 + 64) * 32 + cb;
  // A staging geometry (loop-invariant)
  int rr0 = tid >> 2, cg0 = tid & 3;
  int rr1 = (256 + tid) >> 2, cg1 = (256 + tid) & 3;
  bool tz0 = ((m0 + rr0) & (T - 1)) != 0;
  bool tz1 = ((m0 + rr1) & (T - 1)) != 0;
  const u16* srcA0 = X16 + (size_t)(m0 + rr0) * Kd + cg0 * 8;
  const u16* srcA1 = X16 + (size_t)(m0 + rr1) * Kd + cg1 * 8;
  int wsl0 = lsw(rr0, cg0), wsl1 = lsw(rr1, cg1);
  f32x4 acc[4][4] = {};
  int NT = Kd >> 5;

  // prologue: stage tile 0
  gld_lds16(sB0, &Bs[0][o0]);
  gld_lds16(sB1, &Bs[0][o1]);
  {
    f16x8 c0 = *(const f16x8*)srcA0;
    f16x8 m0v = *(const f16x8*)(mu16 + cg0 * 8);
    f16x8 p0 = {};
    if (tz0) p0 = *(const f16x8*)(srcA0 - Kd);
    *(f16x8*)&As[0][wsl0] = c0 + (p0 - c0) * m0v;
    f16x8 c1 = *(const f16x8*)srcA1;
    f16x8 m1v = *(const f16x8*)(mu16 + cg1 * 8);
    f16x8 p1 = {};
    if (tz1) p1 = *(const f16x8*)(srcA1 - Kd);
    *(f16x8*)&As[0][wsl1] = c1 + (p1 - c1) * m1v;
  }
  __syncthreads();
  int cur = 0;
  for (int kt = 0; kt < NT; kt++){
    bool hn = (kt + 1 < NT);
    f16x8 nc0, np0, nm0, nc1, np1, nm1;
    if (hn){
      int k0 = (kt + 1) << 5;
      gld_lds16(sB0 + k0, &Bs[cur ^ 1][o0]);
      gld_lds16(sB1 + k0, &Bs[cur ^ 1][o1]);
      nc0 = *(const f16x8*)(srcA0 + k0);
      nm0 = *(const f16x8*)(mu16 + k0 + cg0 * 8);
      np0 = f16x8{};
      if (tz0) np0 = *(const f16x8*)(srcA0 + k0 - Kd);
      nc1 = *(const f16x8*)(srcA1 + k0);
      nm1 = *(const f16x8*)(mu16 + k0 + cg1 * 8);
      np1 = f16x8{};
      if (tz1) np1 = *(const f16x8*)(srcA1 + k0 - Kd);
    }
    f16x8 af[4], bf[4];
    #pragma unroll
    for (int mi = 0; mi < 4; mi++) af[mi] = *(const f16x8*)&As[cur][lsw(wr + mi * 16 + lr, kgrp)];
    #pragma unroll
    for (int ni = 0; ni < 4; ni++) bf[ni] = *(const f16x8*)&Bs[cur][lsw(wc + ni * 16 + lr, kgrp)];
    #pragma unroll
    for (int mi = 0; mi < 4; mi++){
      #pragma unroll
      for (int ni = 0; ni < 4; ni++){
        acc[mi][ni] = __builtin_amdgcn_mfma_f32_16x16x32_f16(af[mi], bf[ni], acc[mi][ni], 0, 0, 0);
      }
    }
    if (hn){
      *(f16x8*)&As[cur ^ 1][wsl0] = nc0 + (np0 - nc0) * nm0;
      *(f16x8*)&As[cur ^ 1][wsl1] = nc1 + (np1 - nc1) * nm1;
    }
    __syncthreads();
    cur ^= 1;
  }

  int act = args.act[z];
  const float* bias = args.bias[z];
  u16* outh = args.outh[z];
  int rowb = m0 + wr + (lane >> 4) * 4;
  int colb = n0 + wc + lr;
  #pragma unroll
  for (int mi = 0; mi < 4; mi++){
    #pragma unroll
    for (int ni = 0; ni < 4; ni++){
      int gcol = colb + ni * 16;
      float bv = bias ? bias[gcol] : 0.f;
      #pragma unroll
      for (int i = 0; i < 4; i++){
        int grow = rowb + mi * 16 + i;
        float xv = acc[mi][ni][i] + bv;
        size_t o = (size_t)grow * Nc + gcol;
        if (act == 2) xv = 1.f / (1.f + __expf(-xv));
        outh[o] = f2h(xv);
      }
    }
  }
}

// ---------------- RWKV7 recurrence + groupnorm + gate ----------------
// r23 structure; k-plane removed from the step loop via k = kk * ||k||:
// per-row scalar ls_nrm replaces the K4 LDS reads (4 ds_read_b128 -> 1 b32 + 1 mul).
constexpr int TS = 8;
__global__ __launch_bounds__(256) void k_rwkv(const u16* __restrict__ rb16, const u16* __restrict__ wp16,
                                              const u16* __restrict__ kb16, const u16* __restrict__ vb,
                                              const u16* __restrict__ ab, const u16* __restrict__ gbuf,
                                              const float* __restrict__ gng, const float* __restrict__ gnb,
                                              u16* __restrict__ yg){
  __shared__ __align__(16) float ls_w[TS][64], ls_r[TS][64];
  __shared__ float ls_v[TS][64];
  __shared__ float ls_kk[TS][64], ls_ka[TS][64];
  __shared__ float ls_nrm[TS];
  __shared__ float sa_red[2][4][64];
  __shared__ float y_red[2][4][64];
  int nh = blockIdx.x;
  int n = nh / HH, hh = nh - n * HH;
  int tid = threadIdx.x;
  int wv = __builtin_amdgcn_readfirstlane(tid >> 6);
  int lane = tid & 63;
  float S[16];
  #pragma unroll
  for (int i = 0; i < 16; i++) S[i] = 0.f;
  int dcol = hh * KD + lane;
  float gscale = gng[dcol], gshift = gnb[dcol];
  size_t hbase = (size_t)n * T * D + hh * KD;
  int jbase = wv * 16;
  int strow = tid >> 5;            // one 32-lane half-wave per staged row
  int stcol = (tid & 31) * 2;
  for (int tt = 0; tt < T; tt += TS){
    __syncthreads();   // prior tile fully consumed
    size_t gofs = hbase + (size_t)(tt + strow) * D + stcol;
    u32 w2 = *(const u32*)(wp16 + gofs);
    u32 k2 = *(const u32*)(kb16 + gofs);
    u32 r2 = *(const u32*)(rb16 + gofs);
    u32 v2 = *(const u32*)(vb + gofs);
    u32 a2 = *(const u32*)(ab + gofs);
    float k0 = h2f((u16)(k2 & 0xffffu));
    float k1 = h2f((u16)(k2 >> 16));
    // ||k|| over this row: reduce within the 32-lane half-wave (offsets <=16 stay in-half)
    float ss = fmaf(k0, k0, k1 * k1);
    #pragma unroll
    for (int o = 16; o; o >>= 1) ss += __shfl_xor(ss, o);
    float nrm = sqrtf(ss) + 1e-6f;
    float inv = 1.f / nrm;
    float kk0 = k0 * inv, kk1 = k1 * inv;
    ls_w[strow][stcol]     = __expf(-__expf(h2f((u16)(w2 & 0xffffu))));
    ls_w[strow][stcol + 1] = __expf(-__expf(h2f((u16)(w2 >> 16))));
    ls_r[strow][stcol]     = h2f((u16)(r2 & 0xffffu));
    ls_r[strow][stcol + 1] = h2f((u16)(r2 >> 16));
    ls_v[strow][stcol]     = h2f((u16)(v2 & 0xffffu));
    ls_v[strow][stcol + 1] = h2f((u16)(v2 >> 16));
    ls_kk[strow][stcol]     = kk0;
    ls_kk[strow][stcol + 1] = kk1;
    ls_ka[strow][stcol]     = kk0 * h2f((u16)(a2 & 0xffffu));
    ls_ka[strow][stcol + 1] = kk1 * h2f((u16)(a2 >> 16));
    if ((tid & 31) == 0) ls_nrm[strow] = nrm;
    __syncthreads();
    for (int s = 0; s < TS; s++){
      int sg = tt + s;
      int pb = sg & 1;
      f32x4 W4[4], KK4[4];
      #pragma unroll
      for (int q = 0; q < 4; q++){
        W4[q]  = *(const f32x4*)&ls_w[s][jbase + q * 4];
        KK4[q] = *(const f32x4*)&ls_kk[s][jbase + q * 4];
      }
      float sap = 0.f;
      #pragma unroll
      for (int q = 0; q < 4; q++){
        #pragma unroll
        for (int i = 0; i < 4; i++){
          S[q * 4 + i] *= W4[q][i];
          sap += S[q * 4 + i] * KK4[q][i];
        }
      }
      sa_red[pb][wv][lane] = sap;
      __syncthreads();
      if (wv == 0 && sg > 0){
        int pp = pb ^ 1;
        float y = y_red[pp][0][lane] + y_red[pp][1][lane] + y_red[pp][2][lane] + y_red[pp][3][lane];
        float s1 = y, s2 = y * y;
        #pragma unroll
        for (int o = 32; o; o >>= 1){ s1 += __shfl_xor(s1, o); s2 += __shfl_xor(s2, o); }
        float mean = s1 * (1.f / 64.f);
        float var = s2 * (1.f / 64.f) - mean * mean;
        float yn = (y - mean) * rsqrtf(var + 64e-5f);
        size_t pidx = hbase + (size_t)(sg - 1) * D + lane;
        float gv = h2f(gbuf[pidx]);
        yg[pidx] = f2h((yn * gscale + gshift) * gv);
      }
      float sa = sa_red[pb][0][lane] + sa_red[pb][1][lane] + sa_red[pb][2][lane] + sa_red[pb][3][lane];
      float nsa = -sa;
      float vn = ls_v[s][lane] * ls_nrm[s];   // v * ||k||: folds k = kk*nrm into v
      f32x4 KA4[4], R4[4];
      #pragma unroll
      for (int q = 0; q < 4; q++){
        KA4[q] = *(const f32x4*)&ls_ka[s][jbase + q * 4];
        R4[q]  = *(const f32x4*)&ls_r[s][jbase + q * 4];
      }
      f32x4 KK4b[4];
      #pragma unroll
      for (int q = 0; q < 4; q++) KK4b[q] = *(const f32x4*)&ls_kk[s][jbase + q * 4];
      float yp = 0.f;
      #pragma unroll
      for (int q = 0; q < 4; q++){
        #pragma unroll
        for (int i = 0; i < 4; i++){
          S[q * 4 + i] = fmaf(vn, KK4b[q][i], S[q * 4 + i]);
          S[q * 4 + i] = fmaf(nsa, KA4[q][i], S[q * 4 + i]);
          yp += S[q * 4 + i] * R4[q][i];
        }
      }
      y_red[pb][wv][lane] = yp;
    }
  }
  // drain: GN write for step T-1
  __syncthreads();
  if (wv == 0){
    int pp = (T - 1) & 1;
    float y = y_red[pp][0][lane] + y_red[pp][1][lane] + y_red[pp][2][lane] + y_red[pp][3][lane];
    float s1 = y, s2 = y * y;
    #pragma unroll
    for (int o = 32; o; o >>= 1){ s1 += __shfl_xor(s1, o); s2 += __shfl_xor(s2, o); }
    float mean = s1 * (1.f / 64.f);
    float var = s2 * (1.f / 64.f) - mean * mean;
    float yn = (y - mean) * rsqrtf(var + 64e-5f);
    size_t pidx = hbase + (size_t)(T - 1) * D + lane;
    float gv = h2f(gbuf[pidx]);
    yg[pidx] = f2h((yn * gscale + gshift) * gv);
  }
}

// ---------------- final projection, wave-per-row (4 rows/block) ----------------
__global__ __launch_bounds__(256) void k_proj(const float* __restrict__ Hb, const float* __restrict__ Wp,
                                              const float* __restrict__ bp, float* __restrict__ out){
  int lane = threadIdx.x & 63;
  int row = blockIdx.x * 4 + (threadIdx.x >> 6);
  int p = lane & 15, q = lane >> 4;
  const float* hr = Hb + (size_t)row * D;
  float acc = 0.f;
  #pragma unroll 8
  for (int i = 0; i < 192; i++){
    int d = q * 192 + i;
    acc = fmaf(hr[d], Wp[d * PP + p], acc);
  }
  acc += __shfl_xor(acc, 16);
  acc += __shfl_xor(acc, 32);
  if (q == 0) out[(size_t)row * PP + p] = acc + bp[p];
}

extern "C" void kernel_launch(void* const* d_in, const int* in_sizes, int n_in,
                              void* d_out, int out_size, void* d_ws, size_t ws_size,
                              hipStream_t stream){
  (void)in_sizes; (void)n_in; (void)out_size;
  const float* x       = (const float*)d_in[0];
  const float* W_patch = (const float*)d_in[1];
  const float* b_patch = (const float*)d_in[2];
  const float* ln1_g   = (const float*)d_in[3];
  const float* ln1_b   = (const float*)d_in[4];
  const float* ln2_g   = (const float*)d_in[5];
  const float* ln2_b   = (const float*)d_in[6];
  const float* mu_r    = (const float*)d_in[7];
  const float* mu_w    = (const float*)d_in[8];
  const float* mu_k    = (const float*)d_in[9];
  const float* mu_v    = (const float*)d_in[10];
  const float* mu_a    = (const float*)d_in[11];
  const float* mu_g    = (const float*)d_in[12];
  const float* mu_c    = (const float*)d_in[13];
  const float* Wr      = (const float*)d_in[14];
  const float* Wk      = (const float*)d_in[15];
  const float* Wv      = (const float*)d_in[16];
  const float* Wg      = (const float*)d_in[17];
  const float* Ww      = (const float*)d_in[18];
  const float* w0      = (const float*)d_in[19];
  const float* Wa      = (const float*)d_in[20];
  const float* a0      = (const float*)d_in[21];
  const float* Wo      = (const float*)d_in[22];
  const float* gn_g    = (const float*)d_in[23];
  const float* gn_b    = (const float*)d_in[24];
  const float* Wc1     = (const float*)d_in[25];
  const float* Wc2     = (const float*)d_in[26];
  const float* W_proj  = (const float*)d_in[27];
  const float* b_proj  = (const float*)d_in[28];
  float* out = (float*)d_out;

  char* ws = (char*)d_ws;
  size_t off = 0;
  auto alloc = [&](size_t bytes) -> char* {
    char* p = ws + off;
    off = (off + bytes + 255) & ~(size_t)255;
    return p;
  };

  // --- static region: fp16 transposed weights + pe + mu16 (~18 MB) ---
  const size_t WB = (size_t)D * D * 2;
  u16* WrT  = (u16*)alloc(WB);
  u16* WwT  = (u16*)alloc(WB);
  u16* WkT  = (u16*)alloc(WB);
  u16* WvT  = (u16*)alloc(WB);
  u16* WaT  = (u16*)alloc(WB);
  u16* WgT  = (u16*)alloc(WB);
  u16* WoT  = (u16*)alloc(WB);
  u16* Wc1T = (u16*)alloc((size_t)D * DFF * 2);
  u16* Wc2T = (u16*)alloc((size_t)DFF * D * 2);
  float* pe = (float*)alloc((size_t)T * D * 4);
  u16* mu16 = (u16*)alloc((size_t)6 * D * 2);
  size_t wend = off;

  // --- chunking: per row = h(3072) + xx(1536) + wp(1536) + rb,kb,vb,ab,gb fp16 (7680)
  //     = 13824 B/row. Aliases: mid = xx..kb; ygb = ab; xkb = gb.
  int nch = 1;
  size_t Mc = MROWS;
  while (nch < 128){
    size_t need = wend + Mc * 13824 + 64 * 256;
    if (need <= ws_size) break;
    nch *= 2;
    Mc >>= 1;
  }
  float* hbuf = (float*)alloc(Mc * 768 * 4);
  u16* xx     = (u16*)alloc(Mc * 768 * 2);
  u16* wp     = (u16*)alloc(Mc * 768 * 2);
  u16* rb     = (u16*)alloc(Mc * 768 * 2);
  u16* kb     = (u16*)alloc(Mc * 768 * 2);
  u16* vb     = (u16*)alloc(Mc * 768 * 2);
  u16* ab     = (u16*)alloc(Mc * 768 * 2);
  u16* gb     = (u16*)alloc(Mc * 768 * 2);
  u16* ygb = ab;
  u16* mid = xx;
  u16* xkb = gb;

  // --- one-time prep ---
  dim3 tb(32, 8);
  TpArgs ta;
  ta.src[0] = Wr; ta.dst[0] = WrT;
  ta.src[1] = Ww; ta.dst[1] = WwT;
  ta.src[2] = Wk; ta.dst[2] = WkT;
  ta.src[3] = Wv; ta.dst[3] = WvT;
  ta.src[4] = Wa; ta.dst[4] = WaT;
  ta.src[5] = Wg; ta.dst[5] = WgT;
  ta.src[6] = Wo; ta.dst[6] = WoT;
  k_transpose7<<<dim3(24, 24, 7), tb, 0, stream>>>(ta);
  k_transpose<<<dim3(96, 24), tb, 0, stream>>>(Wc1, Wc1T, D, DFF);
  k_transpose<<<dim3(24, 96), tb, 0, stream>>>(Wc2, Wc2T, DFF, D);
  k_pe<<<dim3(192), dim3(256), 0, stream>>>(pe);
  MuArgs ma;
  ma.mu[0] = mu_r; ma.mu[1] = mu_w; ma.mu[2] = mu_k;
  ma.mu[3] = mu_v; ma.mu[4] = mu_a; ma.mu[5] = mu_g;
  k_mu16<<<dim3(6), dim3(256), 0, stream>>>(ma, mu16);

  MixArgs margs;
  const u16* wts[6] = {WrT, WwT, WkT, WvT, WaT, WgT};
  const float* bss[6] = {nullptr, w0, nullptr, nullptr, a0, nullptr};
  u16* oh[6] = {rb, wp, kb, vb, ab, gb};
  int acts[6] = {0, 1, 0, 0, 2, 2};
  margs.mu16 = mu16;
  for (int z = 0; z < 6; z++){
    margs.b[z] = wts[z];
    margs.bias[z] = bss[z];
    margs.outh[z] = oh[z];
    margs.act[z] = acts[z];
  }

  // --- per-chunk pipeline (sequence-local everywhere) ---
  for (int c = 0; c < nch; ++c){
    const float* xc = x + (size_t)c * Mc * PP;
    float* outc = out + (size_t)c * Mc * PP;
    int mcb = (int)(Mc / 128);

    k_patch_ln<<<dim3((int)(Mc / 4)), dim3(256), 0, stream>>>(xc, W_patch, b_patch, pe, ln1_g, ln1_b, hbuf, xx);

    k_mix_lerp<<<dim3(mcb, 6, 6), 256, 0, stream>>>(xx, margs, D, D);

    k_rwkv<<<dim3((int)(Mc / T) * HH), dim3(256), 0, stream>>>(rb, wp, kb, vb, ab, gb, gn_g, gn_b, ygb);

    k_g16<4><<<dim3(mcb, 6), 256, 0, stream>>>(ygb, WoT, nullptr, hbuf, D, D);

    k_ln2<<<dim3((int)(Mc / 4)), dim3(256), 0, stream>>>(hbuf, ln2_g, ln2_b, mu_c, xkb);
    k_g16<3><<<dim3(mcb, DFF / 128), 256, 0, stream>>>(xkb, Wc1T, mid, nullptr, D, DFF);
    k_g16<4><<<dim3(mcb, 6), 256, 0, stream>>>(mid, Wc2T, nullptr, hbuf, DFF, D);

    k_proj<<<dim3((int)(Mc / 4)), dim3(256), 0, stream>>>(hbuf, W_proj, b_proj, outc);
  }
}

// Round 28
// 1565.612 us; speedup vs baseline: 1.0378x; 1.0378x over previous
//
#include <hip/hip_runtime.h>
#include <hip/hip_bf16.h>
#include <math.h>

typedef unsigned short u16;
typedef unsigned int u32;
typedef _Float16 f16x8 __attribute__((ext_vector_type(8)));
typedef float f32x4 __attribute__((ext_vector_type(4)));

#define DEV static __device__ __forceinline__

constexpr int D = 768;
constexpr int HH = 12;
constexpr int KD = 64;
constexpr int T = 64;
constexpr int NSEQ = 512;
constexpr int MROWS = NSEQ * T;   // 32768
constexpr int DFF = 3072;
constexpr int PP = 16;

DEV u16 f2h(float f){ union{_Float16 h; u16 u;} c; c.h = (_Float16)f; return c.u; }
DEV float h2f(u16 u){ union{u16 u; _Float16 h;} c; c.u = u; return (float)c.h; }
DEV void gld_lds16(const u16* g, u16* l){
  __builtin_amdgcn_global_load_lds((const __attribute__((address_space(1))) void*)g,
                                   (__attribute__((address_space(3))) void*)l, 16, 0, 0);
}
// XOR-swizzled LDS element offset for [128][32] fp16 tiles.
DEV int lsw(int row, int kgrp){ return row * 32 + ((((row >> 2) ^ row) & 3) ^ kgrp) * 8; }

// ---------------- batched transpose: 7 fp32 [D][D] -> fp16 [D][D]^T ----------------
struct TpArgs { const float* src[7]; u16* dst[7]; };
__global__ __launch_bounds__(256) void k_transpose7(TpArgs a){
  __shared__ float tile[32][33];
  int z = blockIdx.z;
  const float* W = a.src[z];
  u16* WT = a.dst[z];
  int c0 = blockIdx.x * 32, r0 = blockIdx.y * 32;
  int tx = threadIdx.x, ty = threadIdx.y;
  #pragma unroll
  for (int i = 0; i < 32; i += 8)
    tile[ty + i][tx] = W[(size_t)(r0 + ty + i) * D + (c0 + tx)];
  __syncthreads();
  #pragma unroll
  for (int i = 0; i < 32; i += 8)
    WT[(size_t)(c0 + ty + i) * D + (r0 + tx)] = f2h(tile[tx][ty + i]);
}

// ---------------- transpose fp32 [R][C] -> fp16 [C][R] ----------------
__global__ __launch_bounds__(256) void k_transpose(const float* __restrict__ W, u16* __restrict__ WT,
                                                   int R, int C){
  __shared__ float tile[32][33];
  int c0 = blockIdx.x * 32, r0 = blockIdx.y * 32;
  int tx = threadIdx.x, ty = threadIdx.y;
  #pragma unroll
  for (int i = 0; i < 32; i += 8)
    tile[ty + i][tx] = W[(size_t)(r0 + ty + i) * C + (c0 + tx)];
  __syncthreads();
  #pragma unroll
  for (int i = 0; i < 32; i += 8)
    WT[(size_t)(c0 + ty + i) * R + (r0 + tx)] = f2h(tile[tx][ty + i]);
}

// ---------------- positional embedding [T][D] ----------------
__global__ void k_pe(float* __restrict__ pe){
  int idx = blockIdx.x * 256 + threadIdx.x;
  if (idx >= T * D) return;
  int t = idx / D, d = idx % D;
  float dv = __expf((float)(d & ~1) * (-9.210340371976184f / (float)D));
  float ang = (float)t * dv;
  pe[idx] = (d & 1) ? cosf(ang) : sinf(ang);
}

// ---------------- fp16 mu planes ----------------
struct MuArgs { const float* mu[6]; };
__global__ __launch_bounds__(256) void k_mu16(MuArgs a, u16* __restrict__ mu16){
  int z = blockIdx.x;
  #pragma unroll
  for (int j = 0; j < 3; j++){
    int d = threadIdx.x + j * 256;
    mu16[z * D + d] = f2h(a.mu[z][d]);
  }
}

// ---------------- patch embed + LN1, wave-per-row: h fp32 + xx fp16 ----------------
__global__ __launch_bounds__(256) void k_patch_ln(const float* __restrict__ x, const float* __restrict__ Wp,
                                                  const float* __restrict__ bp, const float* __restrict__ pe,
                                                  const float* __restrict__ g, const float* __restrict__ b,
                                                  float* __restrict__ h, u16* __restrict__ xx16){
  int lane = threadIdx.x & 63;
  int row = blockIdx.x * 4 + (threadIdx.x >> 6);
  int t = row & (T - 1);
  const float* xr = x + (size_t)row * PP;
  float xs[PP];
  #pragma unroll
  for (int p = 0; p < PP; p++) xs[p] = xr[p];
  float v[12], s = 0.f, sq = 0.f;
  #pragma unroll
  for (int j = 0; j < 12; j++){
    int d = lane + j * 64;
    float acc = bp[d] + pe[t * D + d];
    #pragma unroll
    for (int p = 0; p < PP; p++) acc = fmaf(xs[p], Wp[p * D + d], acc);
    v[j] = acc; s += acc; sq = fmaf(acc, acc, sq);
  }
  #pragma unroll
  for (int o = 32; o; o >>= 1){ s += __shfl_xor(s, o); sq += __shfl_xor(sq, o); }
  float mean = s * (1.f / 768.f);
  float rstd = rsqrtf(sq * (1.f / 768.f) - mean * mean + 1e-5f);
  float* hrow = h + (size_t)row * D;
  u16* xrow = xx16 + (size_t)row * D;
  #pragma unroll
  for (int j = 0; j < 12; j++){
    int d = lane + j * 64;
    hrow[d] = v[j];
    xrow[d] = f2h((v[j] - mean) * rstd * g[d] + b[d]);
  }
}

// ---------------- LN2 + token-shift lerp fused -> fp16 xk ----------------
__global__ __launch_bounds__(256) void k_ln2(const float* __restrict__ X, const float* __restrict__ g,
                                             const float* __restrict__ b, const float* __restrict__ mu,
                                             u16* __restrict__ out){
  int lane = threadIdx.x & 63;
  int row = blockIdx.x * 4 + (threadIdx.x >> 6);
  int t = row & (T - 1);
  const float* xr = X + (size_t)row * D;
  float v[12], s = 0.f, sq = 0.f;
  #pragma unroll
  for (int j = 0; j < 12; j++){ v[j] = xr[lane + j * 64]; s += v[j]; sq += v[j] * v[j]; }
  #pragma unroll
  for (int o = 32; o; o >>= 1){ s += __shfl_xor(s, o); sq += __shfl_xor(sq, o); }
  float mean = s * (1.f / 768.f);
  float rstd = rsqrtf(sq * (1.f / 768.f) - mean * mean + 1e-5f);
  float p[12], meanp = 0.f, rstdp = 0.f;
  if (t){
    const float* xp = xr - D;
    float sp = 0.f, sqp = 0.f;
    #pragma unroll
    for (int j = 0; j < 12; j++){ p[j] = xp[lane + j * 64]; sp += p[j]; sqp += p[j] * p[j]; }
    #pragma unroll
    for (int o = 32; o; o >>= 1){ sp += __shfl_xor(sp, o); sqp += __shfl_xor(sqp, o); }
    meanp = sp * (1.f / 768.f);
    rstdp = rsqrtf(sqp * (1.f / 768.f) - meanp * meanp + 1e-5f);
  }
  u16* orow = out + (size_t)row * D;
  #pragma unroll
  for (int j = 0; j < 12; j++){
    int d = lane + j * 64;
    float cm = (v[j] - mean) * rstd * g[d] + b[d];
    float cp = t ? (p[j] - meanp) * rstdp * g[d] + b[d] : 0.f;
    orow[d] = f2h(cm + (cp - cm) * mu[d]);
  }
}

// ---------------- fp16 GEMM, double-buffered LDS, 1 barrier/K-step (T3 2-phase) ----------------
// ACT: 3 relu^2->f16, 4 add->f32
template<int ACT>
__global__ __launch_bounds__(256) void k_g16(const u16* __restrict__ A, const u16* __restrict__ BT,
                                             u16* __restrict__ outH, float* __restrict__ outF,
                                             int Kd, int Nc){
  __shared__ __align__(16) u16 As[2][128 * 32];
  __shared__ __align__(16) u16 Bs[2][128 * 32];
  int tid = threadIdx.x;
  int m0 = blockIdx.x * 128, n0 = blockIdx.y * 128;
  int wv = tid >> 6, lane = tid & 63;
  int wr = (wv >> 1) * 64, wc = (wv & 1) * 64;
  int lr = lane & 15, kgrp = lane >> 4;
  int r0 = wv * 16 + (lane >> 2);
  int cbg = ((((r0 >> 2) ^ r0) & 3) ^ (lane & 3)) * 8;   // pre-swizzled global col
  const u16* sA0 = A + (size_t)(m0 + r0) * Kd + cbg;
  const u16* sA1 = A + (size_t)(m0 + r0 + 64) * Kd + cbg;
  const u16* sB0 = BT + (size_t)(n0 + r0) * Kd + cbg;
  const u16* sB1 = BT + (size_t)(n0 + r0 + 64) * Kd + cbg;
  int cb = (lane & 3) * 8;
  int o0 = r0 * 32 + cb, o1 = (r0 + 64) * 32 + cb;
  f32x4 acc[4][4] = {};
  int NT = Kd >> 5;

  gld_lds16(sA0, &As[0][o0]);
  gld_lds16(sA1, &As[0][o1]);
  gld_lds16(sB0, &Bs[0][o0]);
  gld_lds16(sB1, &Bs[0][o1]);
  __syncthreads();
  int cur = 0;
  for (int kt = 0; kt < NT; kt++){
    if (kt + 1 < NT){
      int k0 = (kt + 1) << 5;
      gld_lds16(sA0 + k0, &As[cur ^ 1][o0]);
      gld_lds16(sA1 + k0, &As[cur ^ 1][o1]);
      gld_lds16(sB0 + k0, &Bs[cur ^ 1][o0]);
      gld_lds16(sB1 + k0, &Bs[cur ^ 1][o1]);
    }
    f16x8 af[4], bf[4];
    #pragma unroll
    for (int mi = 0; mi < 4; mi++) af[mi] = *(const f16x8*)&As[cur][lsw(wr + mi * 16 + lr, kgrp)];
    #pragma unroll
    for (int ni = 0; ni < 4; ni++) bf[ni] = *(const f16x8*)&Bs[cur][lsw(wc + ni * 16 + lr, kgrp)];
    #pragma unroll
    for (int mi = 0; mi < 4; mi++){
      #pragma unroll
      for (int ni = 0; ni < 4; ni++){
        acc[mi][ni] = __builtin_amdgcn_mfma_f32_16x16x32_f16(af[mi], bf[ni], acc[mi][ni], 0, 0, 0);
      }
    }
    __syncthreads();
    cur ^= 1;
  }

  int rowb = m0 + wr + (lane >> 4) * 4;
  int colb = n0 + wc + lr;
  #pragma unroll
  for (int mi = 0; mi < 4; mi++){
    #pragma unroll
    for (int ni = 0; ni < 4; ni++){
      int gcol = colb + ni * 16;
      #pragma unroll
      for (int i = 0; i < 4; i++){
        int grow = rowb + mi * 16 + i;
        float xv = acc[mi][ni][i];
        size_t o = (size_t)grow * Nc + gcol;
        if (ACT == 3){ float rl = fmaxf(xv, 0.f); outH[o] = f2h(rl * rl); }
        else outF[o] += xv;
      }
    }
  }
}

// ---------------- mixing GEMM: fused fp16 lerp A-stage, double-buffered, async-split ----------------
// act: 0 none->f16, 1 (x+bias)->f16 raw (w preact), 2 sigmoid(x+bias)->f16
struct MixArgs {
  const u16* b[6]; const float* bias[6]; const u16* mu16;
  u16* outh[6]; int act[6];
};
__global__ __launch_bounds__(256) void k_mix_lerp(const u16* __restrict__ X16, MixArgs args, int Kd, int Nc){
  __shared__ __align__(16) u16 As[2][128 * 32];
  __shared__ __align__(16) u16 Bs[2][128 * 32];
  int tid = threadIdx.x, z = blockIdx.z;
  const u16* BT = args.b[z];
  const u16* mu16 = args.mu16 + z * D;
  int m0 = blockIdx.x * 128, n0 = blockIdx.y * 128;
  int wv = tid >> 6, lane = tid & 63;
  int wr = (wv >> 1) * 64, wc = (wv & 1) * 64;
  int lr = lane & 15, kgrp = lane >> 4;
  int r0 = wv * 16 + (lane >> 2);
  int cbg = ((((r0 >> 2) ^ r0) & 3) ^ (lane & 3)) * 8;
  const u16* sB0 = BT + (size_t)(n0 + r0) * Kd + cbg;
  const u16* sB1 = BT + (size_t)(n0 + r0 + 64) * Kd + cbg;
  int cb = (lane & 3) * 8;
  int o0 = r0 * 32 + cb, o1 = (r0 + 64) * 32 + cb;
  int rr0 = tid >> 2, cg0 = tid & 3;
  int rr1 = (256 + tid) >> 2, cg1 = (256 + tid) & 3;
  bool tz0 = ((m0 + rr0) & (T - 1)) != 0;
  bool tz1 = ((m0 + rr1) & (T - 1)) != 0;
  const u16* srcA0 = X16 + (size_t)(m0 + rr0) * Kd + cg0 * 8;
  const u16* srcA1 = X16 + (size_t)(m0 + rr1) * Kd + cg1 * 8;
  int wsl0 = lsw(rr0, cg0), wsl1 = lsw(rr1, cg1);
  f32x4 acc[4][4] = {};
  int NT = Kd >> 5;

  gld_lds16(sB0, &Bs[0][o0]);
  gld_lds16(sB1, &Bs[0][o1]);
  {
    f16x8 c0 = *(const f16x8*)srcA0;
    f16x8 m0v = *(const f16x8*)(mu16 + cg0 * 8);
    f16x8 p0 = {};
    if (tz0) p0 = *(const f16x8*)(srcA0 - Kd);
    *(f16x8*)&As[0][wsl0] = c0 + (p0 - c0) * m0v;
    f16x8 c1 = *(const f16x8*)srcA1;
    f16x8 m1v = *(const f16x8*)(mu16 + cg1 * 8);
    f16x8 p1 = {};
    if (tz1) p1 = *(const f16x8*)(srcA1 - Kd);
    *(f16x8*)&As[0][wsl1] = c1 + (p1 - c1) * m1v;
  }
  __syncthreads();
  int cur = 0;
  for (int kt = 0; kt < NT; kt++){
    bool hn = (kt + 1 < NT);
    f16x8 nc0, np0, nm0, nc1, np1, nm1;
    if (hn){
      int k0 = (kt + 1) << 5;
      gld_lds16(sB0 + k0, &Bs[cur ^ 1][o0]);
      gld_lds16(sB1 + k0, &Bs[cur ^ 1][o1]);
      nc0 = *(const f16x8*)(srcA0 + k0);
      nm0 = *(const f16x8*)(mu16 + k0 + cg0 * 8);
      np0 = f16x8{};
      if (tz0) np0 = *(const f16x8*)(srcA0 + k0 - Kd);
      nc1 = *(const f16x8*)(srcA1 + k0);
      nm1 = *(const f16x8*)(mu16 + k0 + cg1 * 8);
      np1 = f16x8{};
      if (tz1) np1 = *(const f16x8*)(srcA1 + k0 - Kd);
    }
    f16x8 af[4], bf[4];
    #pragma unroll
    for (int mi = 0; mi < 4; mi++) af[mi] = *(const f16x8*)&As[cur][lsw(wr + mi * 16 + lr, kgrp)];
    #pragma unroll
    for (int ni = 0; ni < 4; ni++) bf[ni] = *(const f16x8*)&Bs[cur][lsw(wc + ni * 16 + lr, kgrp)];
    #pragma unroll
    for (int mi = 0; mi < 4; mi++){
      #pragma unroll
      for (int ni = 0; ni < 4; ni++){
        acc[mi][ni] = __builtin_amdgcn_mfma_f32_16x16x32_f16(af[mi], bf[ni], acc[mi][ni], 0, 0, 0);
      }
    }
    if (hn){
      *(f16x8*)&As[cur ^ 1][wsl0] = nc0 + (np0 - nc0) * nm0;
      *(f16x8*)&As[cur ^ 1][wsl1] = nc1 + (np1 - nc1) * nm1;
    }
    __syncthreads();
    cur ^= 1;
  }

  int act = args.act[z];
  const float* bias = args.bias[z];
  u16* outh = args.outh[z];
  int rowb = m0 + wr + (lane >> 4) * 4;
  int colb = n0 + wc + lr;
  #pragma unroll
  for (int mi = 0; mi < 4; mi++){
    #pragma unroll
    for (int ni = 0; ni < 4; ni++){
      int gcol = colb + ni * 16;
      float bv = bias ? bias[gcol] : 0.f;
      #pragma unroll
      for (int i = 0; i < 4; i++){
        int grow = rowb + mi * 16 + i;
        float xv = acc[mi][ni][i] + bv;
        size_t o = (size_t)grow * Nc + gcol;
        if (act == 2) xv = 1.f / (1.f + __expf(-xv));
        outh[o] = f2h(xv);
      }
    }
  }
}

// ---------------- RWKV7 recurrence + groupnorm + gate ----------------
// TWO heads per 256-thread block; per head a 2-wave k-split (S[32]/thread).
// Same barrier count as before but 2x work per barrier. r25 step math.
constexpr int TS = 8;
__global__ __launch_bounds__(256) void k_rwkv(const u16* __restrict__ rb16, const u16* __restrict__ wp16,
                                              const u16* __restrict__ kb16, const u16* __restrict__ vb,
                                              const u16* __restrict__ ab, const u16* __restrict__ gbuf,
                                              const float* __restrict__ gng, const float* __restrict__ gnb,
                                              u16* __restrict__ yg){
  __shared__ __align__(16) float ls_w[2][TS][64], ls_k[2][TS][64], ls_r[2][TS][64];
  __shared__ float ls_v[2][TS][64];
  __shared__ float ls_kk[2][TS][64], ls_ka[2][TS][64];
  __shared__ float sa_red[2][2][2][64];   // [parity][head][khalf][lane]
  __shared__ float y_red[2][2][2][64];
  int nh2 = blockIdx.x;
  constexpr int HP = HH / 2;
  int n = nh2 / HP, hp = nh2 - n * HP;
  int hh0 = hp * 2;
  int tid = threadIdx.x;
  int wv = __builtin_amdgcn_readfirstlane(tid >> 6);
  int lane = tid & 63;
  int hd = wv >> 1, wh = wv & 1;
  float S[32];
  #pragma unroll
  for (int i = 0; i < 32; i++) S[i] = 0.f;
  int dcol = (hh0 + hd) * KD + lane;
  float gscale = gng[dcol], gshift = gnb[dcol];
  size_t hbaseA = (size_t)n * T * D + (size_t)hh0 * KD;
  size_t hbase = hbaseA + (size_t)hd * KD;     // this wave's head
  int jbase = wh * 32;
  int strow = tid >> 5;            // one 32-lane half-wave per staged row
  int stcol = (tid & 31) * 2;
  for (int tt = 0; tt < T; tt += TS){
    __syncthreads();   // prior tile fully consumed
    #pragma unroll
    for (int h2 = 0; h2 < 2; h2++){
      size_t gofs = hbaseA + (size_t)h2 * KD + (size_t)(tt + strow) * D + stcol;
      u32 w2 = *(const u32*)(wp16 + gofs);
      u32 k2 = *(const u32*)(kb16 + gofs);
      u32 r2 = *(const u32*)(rb16 + gofs);
      u32 v2 = *(const u32*)(vb + gofs);
      u32 a2 = *(const u32*)(ab + gofs);
      float k0 = h2f((u16)(k2 & 0xffffu));
      float k1 = h2f((u16)(k2 >> 16));
      float ss = fmaf(k0, k0, k1 * k1);
      #pragma unroll
      for (int o = 16; o; o >>= 1) ss += __shfl_xor(ss, o);
      float inv = 1.f / (sqrtf(ss) + 1e-6f);
      float kk0 = k0 * inv, kk1 = k1 * inv;
      ls_w[h2][strow][stcol]     = __expf(-__expf(h2f((u16)(w2 & 0xffffu))));
      ls_w[h2][strow][stcol + 1] = __expf(-__expf(h2f((u16)(w2 >> 16))));
      ls_k[h2][strow][stcol]     = k0;
      ls_k[h2][strow][stcol + 1] = k1;
      ls_r[h2][strow][stcol]     = h2f((u16)(r2 & 0xffffu));
      ls_r[h2][strow][stcol + 1] = h2f((u16)(r2 >> 16));
      ls_v[h2][strow][stcol]     = h2f((u16)(v2 & 0xffffu));
      ls_v[h2][strow][stcol + 1] = h2f((u16)(v2 >> 16));
      ls_kk[h2][strow][stcol]     = kk0;
      ls_kk[h2][strow][stcol + 1] = kk1;
      ls_ka[h2][strow][stcol]     = kk0 * h2f((u16)(a2 & 0xffffu));
      ls_ka[h2][strow][stcol + 1] = kk1 * h2f((u16)(a2 >> 16));
    }
    __syncthreads();
    for (int s = 0; s < TS; s++){
      int sg = tt + s;
      int pb = sg & 1;
      // PRE: decay + sa partial over this wave's 32 k-columns
      float sap = 0.f;
      #pragma unroll
      for (int q = 0; q < 8; q++){
        f32x4 W4  = *(const f32x4*)&ls_w[hd][s][jbase + q * 4];
        f32x4 KK4 = *(const f32x4*)&ls_kk[hd][s][jbase + q * 4];
        #pragma unroll
        for (int i = 0; i < 4; i++){
          S[q * 4 + i] *= W4[i];
          sap += S[q * 4 + i] * KK4[i];
        }
      }
      sa_red[pb][hd][wh][lane] = sap;
      __syncthreads();
      // deferred GN of step sg-1: one wave per head (wh==0)
      if (wh == 0 && sg > 0){
        int pp = pb ^ 1;
        float y = y_red[pp][hd][0][lane] + y_red[pp][hd][1][lane];
        float s1 = y, s2 = y * y;
        #pragma unroll
        for (int o = 32; o; o >>= 1){ s1 += __shfl_xor(s1, o); s2 += __shfl_xor(s2, o); }
        float mean = s1 * (1.f / 64.f);
        float var = s2 * (1.f / 64.f) - mean * mean;
        float yn = (y - mean) * rsqrtf(var + 64e-5f);
        size_t pidx = hbase + (size_t)(sg - 1) * D + lane;
        float gv = h2f(gbuf[pidx]);
        yg[pidx] = f2h((yn * gscale + gshift) * gv);
      }
      float sa = sa_red[pb][hd][0][lane] + sa_red[pb][hd][1][lane];
      float nsa = -sa;
      float vl = ls_v[hd][s][lane];
      float yp = 0.f;
      #pragma unroll
      for (int q = 0; q < 8; q++){
        f32x4 K4  = *(const f32x4*)&ls_k[hd][s][jbase + q * 4];
        f32x4 KA4 = *(const f32x4*)&ls_ka[hd][s][jbase + q * 4];
        f32x4 R4  = *(const f32x4*)&ls_r[hd][s][jbase + q * 4];
        #pragma unroll
        for (int i = 0; i < 4; i++){
          S[q * 4 + i] = fmaf(vl, K4[i], S[q * 4 + i]);
          S[q * 4 + i] = fmaf(nsa, KA4[i], S[q * 4 + i]);
          yp += S[q * 4 + i] * R4[i];
        }
      }
      y_red[pb][hd][wh][lane] = yp;
    }
  }
  // drain: GN write for step T-1 (one wave per head)
  __syncthreads();
  if (wh == 0){
    int pp = (T - 1) & 1;
    float y = y_red[pp][hd][0][lane] + y_red[pp][hd][1][lane];
    float s1 = y, s2 = y * y;
    #pragma unroll
    for (int o = 32; o; o >>= 1){ s1 += __shfl_xor(s1, o); s2 += __shfl_xor(s2, o); }
    float mean = s1 * (1.f / 64.f);
    float var = s2 * (1.f / 64.f) - mean * mean;
    float yn = (y - mean) * rsqrtf(var + 64e-5f);
    size_t pidx = hbase + (size_t)(T - 1) * D + lane;
    float gv = h2f(gbuf[pidx]);
    yg[pidx] = f2h((yn * gscale + gshift) * gv);
  }
}

// ---------------- final projection, wave-per-row (4 rows/block) ----------------
__global__ __launch_bounds__(256) void k_proj(const float* __restrict__ Hb, const float* __restrict__ Wp,
                                              const float* __restrict__ bp, float* __restrict__ out){
  int lane = threadIdx.x & 63;
  int row = blockIdx.x * 4 + (threadIdx.x >> 6);
  int p = lane & 15, q = lane >> 4;
  const float* hr = Hb + (size_t)row * D;
  float acc = 0.f;
  #pragma unroll 8
  for (int i = 0; i < 192; i++){
    int d = q * 192 + i;
    acc = fmaf(hr[d], Wp[d * PP + p], acc);
  }
  acc += __shfl_xor(acc, 16);
  acc += __shfl_xor(acc, 32);
  if (q == 0) out[(size_t)row * PP + p] = acc + bp[p];
}

extern "C" void kernel_launch(void* const* d_in, const int* in_sizes, int n_in,
                              void* d_out, int out_size, void* d_ws, size_t ws_size,
                              hipStream_t stream){
  (void)in_sizes; (void)n_in; (void)out_size;
  const float* x       = (const float*)d_in[0];
  const float* W_patch = (const float*)d_in[1];
  const float* b_patch = (const float*)d_in[2];
  const float* ln1_g   = (const float*)d_in[3];
  const float* ln1_b   = (const float*)d_in[4];
  const float* ln2_g   = (const float*)d_in[5];
  const float* ln2_b   = (const float*)d_in[6];
  const float* mu_r    = (const float*)d_in[7];
  const float* mu_w    = (const float*)d_in[8];
  const float* mu_k    = (const float*)d_in[9];
  const float* mu_v    = (const float*)d_in[10];
  const float* mu_a    = (const float*)d_in[11];
  const float* mu_g    = (const float*)d_in[12];
  const float* mu_c    = (const float*)d_in[13];
  const float* Wr      = (const float*)d_in[14];
  const float* Wk      = (const float*)d_in[15];
  const float* Wv      = (const float*)d_in[16];
  const float* Wg      = (const float*)d_in[17];
  const float* Ww      = (const float*)d_in[18];
  const float* w0      = (const float*)d_in[19];
  const float* Wa      = (const float*)d_in[20];
  const float* a0      = (const float*)d_in[21];
  const float* Wo      = (const float*)d_in[22];
  const float* gn_g    = (const float*)d_in[23];
  const float* gn_b    = (const float*)d_in[24];
  const float* Wc1     = (const float*)d_in[25];
  const float* Wc2     = (const float*)d_in[26];
  const float* W_proj  = (const float*)d_in[27];
  const float* b_proj  = (const float*)d_in[28];
  float* out = (float*)d_out;

  char* ws = (char*)d_ws;
  size_t off = 0;
  auto alloc = [&](size_t bytes) -> char* {
    char* p = ws + off;
    off = (off + bytes + 255) & ~(size_t)255;
    return p;
  };

  // --- static region: fp16 transposed weights + pe + mu16 (~18 MB) ---
  const size_t WB = (size_t)D * D * 2;
  u16* WrT  = (u16*)alloc(WB);
  u16* WwT  = (u16*)alloc(WB);
  u16* WkT  = (u16*)alloc(WB);
  u16* WvT  = (u16*)alloc(WB);
  u16* WaT  = (u16*)alloc(WB);
  u16* WgT  = (u16*)alloc(WB);
  u16* WoT  = (u16*)alloc(WB);
  u16* Wc1T = (u16*)alloc((size_t)D * DFF * 2);
  u16* Wc2T = (u16*)alloc((size_t)DFF * D * 2);
  float* pe = (float*)alloc((size_t)T * D * 4);
  u16* mu16 = (u16*)alloc((size_t)6 * D * 2);
  size_t wend = off;

  // --- chunking: per row = h(3072) + xx(1536) + wp(1536) + rb,kb,vb,ab,gb fp16 (7680)
  //     = 13824 B/row. Aliases: mid = xx..kb; ygb = ab; xkb = gb.
  int nch = 1;
  size_t Mc = MROWS;
  while (nch < 128){
    size_t need = wend + Mc * 13824 + 64 * 256;
    if (need <= ws_size) break;
    nch *= 2;
    Mc >>= 1;
  }
  float* hbuf = (float*)alloc(Mc * 768 * 4);
  u16* xx     = (u16*)alloc(Mc * 768 * 2);
  u16* wp     = (u16*)alloc(Mc * 768 * 2);
  u16* rb     = (u16*)alloc(Mc * 768 * 2);
  u16* kb     = (u16*)alloc(Mc * 768 * 2);
  u16* vb     = (u16*)alloc(Mc * 768 * 2);
  u16* ab     = (u16*)alloc(Mc * 768 * 2);
  u16* gb     = (u16*)alloc(Mc * 768 * 2);
  u16* ygb = ab;
  u16* mid = xx;
  u16* xkb = gb;

  // --- one-time prep ---
  dim3 tb(32, 8);
  TpArgs ta;
  ta.src[0] = Wr; ta.dst[0] = WrT;
  ta.src[1] = Ww; ta.dst[1] = WwT;
  ta.src[2] = Wk; ta.dst[2] = WkT;
  ta.src[3] = Wv; ta.dst[3] = WvT;
  ta.src[4] = Wa; ta.dst[4] = WaT;
  ta.src[5] = Wg; ta.dst[5] = WgT;
  ta.src[6] = Wo; ta.dst[6] = WoT;
  k_transpose7<<<dim3(24, 24, 7), tb, 0, stream>>>(ta);
  k_transpose<<<dim3(96, 24), tb, 0, stream>>>(Wc1, Wc1T, D, DFF);
  k_transpose<<<dim3(24, 96), tb, 0, stream>>>(Wc2, Wc2T, DFF, D);
  k_pe<<<dim3(192), dim3(256), 0, stream>>>(pe);
  MuArgs ma;
  ma.mu[0] = mu_r; ma.mu[1] = mu_w; ma.mu[2] = mu_k;
  ma.mu[3] = mu_v; ma.mu[4] = mu_a; ma.mu[5] = mu_g;
  k_mu16<<<dim3(6), dim3(256), 0, stream>>>(ma, mu16);

  MixArgs margs;
  const u16* wts[6] = {WrT, WwT, WkT, WvT, WaT, WgT};
  const float* bss[6] = {nullptr, w0, nullptr, nullptr, a0, nullptr};
  u16* oh[6] = {rb, wp, kb, vb, ab, gb};
  int acts[6] = {0, 1, 0, 0, 2, 2};
  margs.mu16 = mu16;
  for (int z = 0; z < 6; z++){
    margs.b[z] = wts[z];
    margs.bias[z] = bss[z];
    margs.outh[z] = oh[z];
    margs.act[z] = acts[z];
  }

  // --- per-chunk pipeline (sequence-local everywhere) ---
  for (int c = 0; c < nch; ++c){
    const float* xc = x + (size_t)c * Mc * PP;
    float* outc = out + (size_t)c * Mc * PP;
    int mcb = (int)(Mc / 128);

    k_patch_ln<<<dim3((int)(Mc / 4)), dim3(256), 0, stream>>>(xc, W_patch, b_patch, pe, ln1_g, ln1_b, hbuf, xx);

    k_mix_lerp<<<dim3(mcb, 6, 6), 256, 0, stream>>>(xx, margs, D, D);

    k_rwkv<<<dim3((int)(Mc / T) * (HH / 2)), dim3(256), 0, stream>>>(rb, wp, kb, vb, ab, gb, gn_g, gn_b, ygb);

    k_g16<4><<<dim3(mcb, 6), 256, 0, stream>>>(ygb, WoT, nullptr, hbuf, D, D);

    k_ln2<<<dim3((int)(Mc / 4)), dim3(256), 0, stream>>>(hbuf, ln2_g, ln2_b, mu_c, xkb);
    k_g16<3><<<dim3(mcb, DFF / 128), 256, 0, stream>>>(xkb, Wc1T, mid, nullptr, D, DFF);
    k_g16<4><<<dim3(mcb, 6), 256, 0, stream>>>(mid, Wc2T, nullptr, hbuf, DFF, D);

    k_proj<<<dim3((int)(Mc / 4)), dim3(256), 0, stream>>>(hbuf, W_proj, b_proj, outc);
  }
}